// Round 5
// baseline (72.755 us; speedup 1.0000x reference)
//
#include <hip/hip_runtime.h>

#define DEV __device__ __forceinline__

// descending compare-exchange
DEV void ce_desc(float &a, float &b) {
    float hi = fmaxf(a, b);
    float lo = fminf(a, b);
    a = hi;
    b = lo;
}

// Batcher odd-even mergesort generated for n=32, pruned to 27 wires
// (valid: virtual pads = -inf at wires 27..31 never move, so every
// comparator touching wire >= 27 is a no-op). Descending, fully
// unrolled -> all indices compile-time constants -> stays in VGPRs.
// Operates on TWO independent arrays in lockstep: every layer already
// has ~13 independent comparators per array, and pairing the arrays
// doubles the independent stream count on the serial critical path.
DEV void sort27x2_desc(float (&a)[27], float (&b)[27]) {
#pragma unroll
    for (int p = 1; p < 32; p <<= 1) {
#pragma unroll
        for (int k = p; k >= 1; k >>= 1) {
#pragma unroll
            for (int j = k % p; j + k < 32; j += 2 * k) {
#pragma unroll
                for (int i = 0; i < k; ++i) {
                    if ((i + j + k) < 27 &&
                        (i + j) / (2 * p) == (i + j + k) / (2 * p)) {
                        ce_desc(a[i + j], a[i + j + k]);
                        ce_desc(b[i + j], b[i + j + k]);
                    }
                }
            }
        }
    }
}

// s[0..26] = w sorted descending (the 54 z-values are 3.5 +- w).
// spike - 3.5 = min over m=1..54 of (g - Q)/m with
//   Q = Q_m (sum of m largest w)  for m <= 27,
//   Q = Q_{54-m}                  for m > 27.
// (The +3.5 cancels in tp - tm, so we never add it.)
// D tracks g - Q_i directly; nested fminf is v_min3_f32-fusable.
DEV float spike_best(const float (&s)[27], float g) {
    float D = g;
    float best = D * (1.0f / 54.0f);  // m = 54 (Q_0 = 0)
#pragma unroll
    for (int i = 1; i <= 26; ++i) {
        D -= s[i - 1];
        const float c0 = D * (1.0f / (float)i);         // m = i
        const float c1 = D * (1.0f / (float)(54 - i));  // m = 54 - i
        best = fminf(fminf(best, c0), c1);              // -> v_min3_f32
    }
    D -= s[26];
    best = fminf(best, D * (1.0f / 27.0f));             // m = 27
    return best;
}

__global__ __launch_bounds__(256) void spikeconv_kernel(
        const float* __restrict__ X,      // [8,32,32,3]
        const float* __restrict__ K,      // [27,64]
        const int* __restrict__ gamma_p,  // scalar
        float* __restrict__ O) {          // [8,32,32,64]
    const int f = threadIdx.x & 63;
    // All 64 lanes of a wave share one pid (tid>>6 is wave-constant):
    // readfirstlane marks it uniform -> X addressing goes SALU, X loads
    // go s_load (SMEM pipe), boundary select becomes scalar.
    const int pid =
        __builtin_amdgcn_readfirstlane(blockIdx.x * 4 + (threadIdx.x >> 6));
    const int b = pid >> 10;
    const int h = (pid >> 5) & 31;
    const int w = pid & 31;
    const float g = (float)(*gamma_p);

    float sp[27];  // |p + 0.5k|
    float sm[27];  // |p - 0.5k|
    const float* __restrict__ Kf = K + f;

#pragma unroll
    for (int di = 0; di < 3; ++di) {
#pragma unroll
        for (int dj = 0; dj < 3; ++dj) {
            const int y = h + di - 1;
            const int x = w + dj - 1;
            const bool inb = ((unsigned)y < 32u) & ((unsigned)x < 32u);
            // clamp to a valid address, select 0 after the load (scalar,
            // branchless, never reads out of bounds)
            const int yc = min(max(y, 0), 31);
            const int xc = min(max(x, 0), 31);
            const float* src = X + (((b * 32 + yc) * 32 + xc) * 3);
#pragma unroll
            for (int c = 0; c < 3; ++c) {
                const int d = (di * 3 + dj) * 3 + c;
                const float pv = inb ? src[c] : 0.0f;  // uniform scalar select
                const float kv = Kf[d * 64];           // coalesced over f
                // fma with one SGPR operand (pv) is legal
                sp[d] = fabsf(fmaf(0.5f, kv, pv));
                sm[d] = fabsf(fmaf(-0.5f, kv, pv));
            }
        }
    }

    // fused dual sort: two independent CE streams per network layer
    sort27x2_desc(sp, sm);

    const float bp = spike_best(sp, g);
    const float bm = spike_best(sm, g);

    O[(pid << 6) + f] = fmaxf(bp - bm, 0.0f);  // relu, coalesced store
}

extern "C" void kernel_launch(void* const* d_in, const int* in_sizes, int n_in,
                              void* d_out, int out_size, void* d_ws, size_t ws_size,
                              hipStream_t stream) {
    const float* X = (const float*)d_in[0];        // 8*32*32*3
    const float* K = (const float*)d_in[1];        // 27*64
    const int* gamma_p = (const int*)d_in[2];      // scalar int
    float* O = (float*)d_out;                      // 8*32*32*64

    // 8192 patches * 64 filters = 524288 threads; 4 patches per 256-thread block.
    dim3 grid(2048), block(256);
    hipLaunchKernelGGL(spikeconv_kernel, grid, block, 0, stream, X, K, gamma_p, O);
}

// Round 6
// 71.897 us; speedup vs baseline: 1.0119x; 1.0119x over previous
//
#include <hip/hip_runtime.h>

#define DEV __device__ __forceinline__

// descending compare-exchange
DEV void ce_desc(float &a, float &b) {
    float hi = fmaxf(a, b);
    float lo = fminf(a, b);
    a = hi;
    b = lo;
}

// first-layer CE that also takes |.| of both inputs: compiles to
// v_max_f32 d,|a|,|b| / v_min_f32 d,|a|,|b| (abs = free src modifier)
DEV void ce_desc_abs(float &a, float &b) {
    float hi = fmaxf(fabsf(a), fabsf(b));
    float lo = fminf(fabsf(a), fabsf(b));
    a = hi;
    b = lo;
}

// Batcher odd-even mergesort generated for n=32, pruned to 27 wires
// (valid: virtual pads = -inf at wires 27..31 never move, so every
// comparator touching wire >= 27 is a no-op). Descending, fully
// unrolled -> all indices compile-time constants -> stays in VGPRs.
// Inputs are SIGNED; the first layer (p=1: disjoint pairs (2i,2i+1))
// applies abs via free source modifiers; wire 26's partner is pruned,
// so it gets one explicit fabsf. Two independent arrays in lockstep
// for ILP=2 on the serial critical path.
DEV void sort27x2_desc_abs(float (&a)[27], float (&b)[27]) {
    // layer p=1 (k=1): pairs (0,1)..(24,25); wire 26 untouched
#pragma unroll
    for (int i = 0; i < 13; ++i) {
        ce_desc_abs(a[2 * i], a[2 * i + 1]);
        ce_desc_abs(b[2 * i], b[2 * i + 1]);
    }
    a[26] = fabsf(a[26]);
    b[26] = fabsf(b[26]);
    // remaining layers p = 2,4,8,16
#pragma unroll
    for (int p = 2; p < 32; p <<= 1) {
#pragma unroll
        for (int k = p; k >= 1; k >>= 1) {
#pragma unroll
            for (int j = k % p; j + k < 32; j += 2 * k) {
#pragma unroll
                for (int i = 0; i < k; ++i) {
                    if ((i + j + k) < 27 &&
                        (i + j) / (2 * p) == (i + j + k) / (2 * p)) {
                        ce_desc(a[i + j], a[i + j + k]);
                        ce_desc(b[i + j], b[i + j + k]);
                    }
                }
            }
        }
    }
}

// s[0..26] = w sorted descending (the 54 z-values are 3.5 +- w).
// spike - 3.5 = min over m=1..54 of (g - Q)/m with
//   Q = Q_m (sum of m largest w)  for m <= 27,
//   Q = Q_{54-m}                  for m > 27.
// (The +3.5 cancels in tp - tm, so we never add it.)
// D tracks g - Q_i directly; nested fminf is v_min3_f32-fusable.
DEV float spike_best(const float (&s)[27], float g) {
    float D = g;
    float best = D * (1.0f / 54.0f);  // m = 54 (Q_0 = 0)
#pragma unroll
    for (int i = 1; i <= 26; ++i) {
        D -= s[i - 1];
        const float c0 = D * (1.0f / (float)i);         // m = i
        const float c1 = D * (1.0f / (float)(54 - i));  // m = 54 - i
        best = fminf(fminf(best, c0), c1);              // -> v_min3_f32
    }
    D -= s[26];
    best = fminf(best, D * (1.0f / 27.0f));             // m = 27
    return best;
}

__global__ __launch_bounds__(256) void spikeconv_kernel(
        const float* __restrict__ X,      // [8,32,32,3]
        const float* __restrict__ K,      // [27,64]
        const int* __restrict__ gamma_p,  // scalar
        float* __restrict__ O) {          // [8,32,32,64]
    const int f = threadIdx.x & 63;
    // All 64 lanes of a wave share one pid (tid>>6 is wave-constant):
    // readfirstlane marks it uniform -> X addressing goes SALU, X loads
    // go s_load (SMEM pipe), boundary select becomes scalar.
    const int pid =
        __builtin_amdgcn_readfirstlane(blockIdx.x * 4 + (threadIdx.x >> 6));
    const int b = pid >> 10;
    const int h = (pid >> 5) & 31;
    const int w = pid & 31;
    const float g = (float)(*gamma_p);

    float sp[27];  // p + 0.5k (signed; abs'd in first sort layer)
    float sm[27];  // p - 0.5k (signed)
    const float* __restrict__ Kf = K + f;

#pragma unroll
    for (int di = 0; di < 3; ++di) {
#pragma unroll
        for (int dj = 0; dj < 3; ++dj) {
            const int y = h + di - 1;
            const int x = w + dj - 1;
            const bool inb = ((unsigned)y < 32u) & ((unsigned)x < 32u);
            // clamp to a valid address, select 0 after the load (scalar,
            // branchless, never reads out of bounds)
            const int yc = min(max(y, 0), 31);
            const int xc = min(max(x, 0), 31);
            const float* src = X + (((b * 32 + yc) * 32 + xc) * 3);
#pragma unroll
            for (int c = 0; c < 3; ++c) {
                const int d = (di * 3 + dj) * 3 + c;
                const float pv = inb ? src[c] : 0.0f;  // uniform scalar select
                const float kv = Kf[d * 64];           // coalesced over f
                // fma with one SGPR operand (pv) is legal
                sp[d] = fmaf(0.5f, kv, pv);
                sm[d] = fmaf(-0.5f, kv, pv);
            }
        }
    }

    // fused dual sort (abs folded into first layer's source modifiers)
    sort27x2_desc_abs(sp, sm);

    const float bp = spike_best(sp, g);
    const float bm = spike_best(sm, g);

    O[(pid << 6) + f] = fmaxf(bp - bm, 0.0f);  // relu, coalesced store
}

extern "C" void kernel_launch(void* const* d_in, const int* in_sizes, int n_in,
                              void* d_out, int out_size, void* d_ws, size_t ws_size,
                              hipStream_t stream) {
    const float* X = (const float*)d_in[0];        // 8*32*32*3
    const float* K = (const float*)d_in[1];        // 27*64
    const int* gamma_p = (const int*)d_in[2];      // scalar int
    float* O = (float*)d_out;                      // 8*32*32*64

    // 8192 patches * 64 filters = 524288 threads; 4 patches per 256-thread block.
    dim3 grid(2048), block(256);
    hipLaunchKernelGGL(spikeconv_kernel, grid, block, 0, stream, X, K, gamma_p, O);
}